// Round 4
// baseline (41.050 us; speedup 1.0000x reference)
//
#include <hip/hip_runtime.h>
#include <stdint.h>

#define NW 169   // 13*13 windows

__device__ __forceinline__ float qw128(float x) {
    // fake_quant(w, 128, 8): clip(round(w*128), -128, 127)/128   (round = half-to-even)
    float r = rintf(x * 128.f);
    r = fminf(fmaxf(r, -128.f), 127.f);
    return r * 0.0078125f;
}
__device__ __forceinline__ float qb16384(float x) {
    // fake_quant(b, 128*128, 32): round(b*16384)/16384 (int32 clamp unreachable here)
    return rintf(x * 16384.f) * 6.103515625e-05f;
}

// ONE kernel. Heterogeneous grid of 256-thread blocks:
//   [0, 2048)      : 4 boards/block (1 wave each): ballot -> hash -> f32 gather with
//                    inline exact quantization -> clamp-sum -> tiny MLP -> v out
//   [2048, 3848)   : zero the policy plane (d_out poisoned before timing)
// No inter-kernel dependency, no prep pass over the table, no workspace traffic.
__global__ void nnue_kernel(const int* __restrict__ board,
                            const float* __restrict__ emb,
                            const float* __restrict__ w1, const float* __restrict__ b1,
                            const float* __restrict__ w2, const float* __restrict__ b2,
                            const float* __restrict__ w3, const float* __restrict__ b3,
                            float* __restrict__ vout, float4* __restrict__ policy)
{
    int tid = threadIdx.x;
    if (blockIdx.x >= 2048) {                            // policy zero section
        int i = (blockIdx.x - 2048) * 256 + tid;         // 460800 float4 total
        policy[i] = make_float4(0.f, 0.f, 0.f, 0.f);
        return;                                          // whole block exits pre-barrier
    }

    __shared__ float w1T[32][32], w2T[32][32], w3T[32][4];   // transposed: [k][j]
    __shared__ float b1q[32], b2q[32], b3q[4];
    // Wave-private below (indexed by wv, produced+consumed by same wave):
    // intra-wave LDS RAW is ordered by lgkmcnt; no block barrier needed after staging.
    __shared__ unsigned long long ballots[4][8];
    __shared__ int hashidx[4][176];
    __shared__ float vlds[4][32], h1lds[4][32], h2lds[4][32];

    for (int i = tid; i < 1024; i += 256) {
        int j = i & 31, k = i >> 5;
        w1T[k][j] = qw128(w1[j * 32 + k]);
        w2T[k][j] = qw128(w2[j * 32 + k]);
    }
    if (tid < 96) { int k = tid & 31, j = tid >> 5; w3T[k][j] = qw128(w3[j * 32 + k]); }
    if (tid < 32) { b1q[tid] = qb16384(b1[tid]); b2q[tid] = qb16384(b2[tid]); }
    if (tid < 3)  b3q[tid] = qb16384(b3[tid]);
    __syncthreads();                                     // ONLY block-wide barrier

    int wv = tid >> 6, lane = tid & 63;
    int b = blockIdx.x * 4 + wv;                         // 2048 blocks * 4 waves = 8192 boards
    const int* bp = board + b * 450;

    // phase 1: pack 450 cells into 8x u64 via ballot (coalesced dword loads)
#pragma unroll
    for (int t = 0; t < 8; ++t) {
        int n = t * 64 + lane;
        int cell = (n < 450) ? bp[n] : 0;
        unsigned long long m = __ballot(cell != 0);
        if (lane == 0) ballots[wv][t] = m;
    }

    // phase 2: 169 window hashes; bit f=9c+3i+j of idx = cell(c, wi+i, wj+j)
#pragma unroll
    for (int t = 0; t < 3; ++t) {
        int w = t * 64 + lane;
        if (w < NW) {
            int wi = w / 13;
            int wj = w - wi * 13;
            int idx = 0;
#pragma unroll
            for (int c = 0; c < 2; ++c) {
#pragma unroll
                for (int i = 0; i < 3; ++i) {
                    int s = c * 225 + (wi + i) * 15;     // bit start of row (c, wi+i)
                    int word = s >> 6, off = s & 63;
                    unsigned long long lo = ballots[wv][word];
                    unsigned long long hi = ballots[wv][word + 1];
                    // (lo>>off)|(hi<<(64-off)); double-shift avoids UB, 0 at off==0
                    unsigned long long bits = (lo >> off) | ((hi << 1) << (63 - off));
                    idx |= (int)((bits >> wj) & 7ull) << (9 * c + 3 * i);
                }
            }
            hashidx[wv][w] = idx;
        }
    }

    // phase 3: gather f32 rows, quantize inline (exact), accumulate integer-valued f32.
    // lane covers channels [4*c0, 4*c0+4); group g handles windows g, g+8, g+16, ...
    int c0 = lane & 7;
    int g = lane >> 3;
    const float* basef = emb + c0 * 4;
    float a0 = 0.f, a1 = 0.f, a2 = 0.f, a3 = 0.f;        // sums of ints, |.| <= 21632: exact
#pragma unroll 4
    for (int it = 0; it < 22; ++it) {
        int w = it * 8 + g;
        if (w < NW) {
            int idx = hashidx[wv][w];
            float4 f = *(const float4*)(basef + (size_t)idx * 32);
            // q = round(clip(x, -1, 127/128) * 128) in [-128,127]; min/max fuse to med3
            a0 += rintf(fminf(fmaxf(f.x, -1.f), 0.9921875f) * 128.f);
            a1 += rintf(fminf(fmaxf(f.y, -1.f), 0.9921875f) * 128.f);
            a2 += rintf(fminf(fmaxf(f.z, -1.f), 0.9921875f) * 128.f);
            a3 += rintf(fminf(fmaxf(f.w, -1.f), 0.9921875f) * 128.f);
        }
    }
    // reduce across the 8 window-groups (lanes sharing c0); integer sums stay exact
#pragma unroll
    for (int off = 8; off <= 32; off <<= 1) {
        a0 += __shfl_xor(a0, off);
        a1 += __shfl_xor(a1, off);
        a2 += __shfl_xor(a2, off);
        a3 += __shfl_xor(a3, off);
    }
    if (lane < 8) {                                      // lane == c0 here
        // clip(v, -1, 127/128) == clamp(S, -128, 127)/128 exactly
        vlds[wv][lane * 4 + 0] = fminf(fmaxf(a0, -128.f), 127.f) * 0.0078125f;
        vlds[wv][lane * 4 + 1] = fminf(fmaxf(a1, -128.f), 127.f) * 0.0078125f;
        vlds[wv][lane * 4 + 2] = fminf(fmaxf(a2, -128.f), 127.f) * 0.0078125f;
        vlds[wv][lane * 4 + 3] = fminf(fmaxf(a3, -128.f), 127.f) * 0.0078125f;
    }

    // MLP: lane jj in [0,32) computes output jj; halves split k, combine via shfl_xor(32)
    int jj = lane & 31, hf = lane >> 5;
    float s1 = 0.f;
#pragma unroll
    for (int k2 = 0; k2 < 16; ++k2) {
        int k = hf * 16 + k2;
        s1 = fmaf(vlds[wv][k], w1T[k][jj], s1);
    }
    s1 += __shfl_xor(s1, 32);
    s1 += b1q[jj];
    s1 = fminf(fmaxf(s1, 0.f), 0.9921875f);
    if (lane < 32) h1lds[wv][jj] = s1;

    float s2 = 0.f;
#pragma unroll
    for (int k2 = 0; k2 < 16; ++k2) {
        int k = hf * 16 + k2;
        s2 = fmaf(h1lds[wv][k], w2T[k][jj], s2);
    }
    s2 += __shfl_xor(s2, 32);
    s2 += b2q[jj];
    s2 = fminf(fmaxf(s2, 0.f), 0.9921875f);
    if (lane < 32) h2lds[wv][jj] = s2;

    float s3 = 0.f;
    if (jj < 3) {
#pragma unroll
        for (int k2 = 0; k2 < 16; ++k2) {
            int k = hf * 16 + k2;
            s3 = fmaf(h2lds[wv][k], w3T[k][jj], s3);
        }
    }
    s3 += __shfl_xor(s3, 32);
    if (lane < 3) vout[b * 3 + lane] = s3 + b3q[lane];
}

extern "C" void kernel_launch(void* const* d_in, const int* in_sizes, int n_in,
                              void* d_out, int out_size, void* d_ws, size_t ws_size,
                              hipStream_t stream) {
    const int*   board = (const int*)d_in[0];
    const float* emb   = (const float*)d_in[1];
    const float* w1    = (const float*)d_in[2];
    const float* b1    = (const float*)d_in[3];
    const float* w2    = (const float*)d_in[4];
    const float* b2    = (const float*)d_in[5];
    const float* w3    = (const float*)d_in[6];
    const float* b3    = (const float*)d_in[7];
    float* out = (float*)d_out;

    // v = out[0 : 8192*3], policy = out[24576 : 24576+1843200]
    nnue_kernel<<<3848, 256, 0, stream>>>(board, emb, w1, b1, w2, b2, w3, b3,
                                          out, (float4*)(out + 24576));
}

// Round 6
// 40.540 us; speedup vs baseline: 1.0126x; 1.0126x over previous
//
#include <hip/hip_runtime.h>
#include <stdint.h>

#define NW 169   // 13*13 windows

typedef float f32x4 __attribute__((ext_vector_type(4)));  // nontemporal-store-compatible

__device__ __forceinline__ float qw128(float x) {
    // fake_quant(w, 128, 8): clip(round(w*128), -128, 127)/128   (round = half-to-even)
    float r = rintf(x * 128.f);
    r = fminf(fmaxf(r, -128.f), 127.f);
    return r * 0.0078125f;
}
__device__ __forceinline__ float qb16384(float x) {
    // fake_quant(b, 128*128, 32): round(b*16384)/16384 (int32 clamp unreachable here)
    return rintf(x * 16384.f) * 6.103515625e-05f;
}

// Fused prep, heterogeneous grid of 256-thread blocks:
//   [0, 2048)    : quantize 2^18 x 32 emb table -> biased uint8 (16 floats/thread)
//   [2048, 3848) : zero the policy plane (nontemporal; d_out poisoned before timing)
__global__ void prep_kernel(const float* __restrict__ emb, uint8_t* __restrict__ q,
                            f32x4* __restrict__ policy) {
    int bid = blockIdx.x;
    int tid = threadIdx.x;
    if (bid >= 2048) {                                   // policy zero section
        int i = (bid - 2048) * 256 + tid;                // 460800 float4 total
        f32x4 z = {0.f, 0.f, 0.f, 0.f};
        __builtin_nontemporal_store(z, &policy[i]);
        return;
    }
    int i = bid * 256 + tid;                             // 16 floats per thread
    const float4* in4 = (const float4*)emb + (size_t)i * 4;
    uint32_t words[4];
#pragma unroll
    for (int t = 0; t < 4; ++t) {
        float4 f = in4[t];
        float v[4] = {f.x, f.y, f.z, f.w};
        uint32_t w = 0;
#pragma unroll
        for (int j = 0; j < 4; ++j) {
            float x = fminf(fmaxf(v[j], -1.f), 0.9921875f);
            int r = (int)rintf(x * 128.f) + 128;         // [0,255]
            w |= ((uint32_t)r & 0xFFu) << (8 * j);
        }
        words[t] = w;
    }
    ((uint4*)q)[i] = make_uint4(words[0], words[1], words[2], words[3]);
}

__global__ __launch_bounds__(256)
void nnue_kernel(const int* __restrict__ board,
                 const uint8_t* __restrict__ embq,
                 const float* __restrict__ w1, const float* __restrict__ b1,
                 const float* __restrict__ w2, const float* __restrict__ b2,
                 const float* __restrict__ w3, const float* __restrict__ b3,
                 float* __restrict__ vout)
{
    __shared__ float w1T[32][32], w2T[32][32], w3T[32][4];   // transposed: [k][j]
    __shared__ float b1q[32], b2q[32], b3q[4];
    // Wave-private below (indexed by wv, produced+consumed by same wave):
    // intra-wave LDS RAW ordered by lgkmcnt; no block barrier needed after staging.
    __shared__ unsigned long long ballots[4][8];
    __shared__ int hashoff[4][192];                          // idx<<5; [169,192) padded 0
    __shared__ float vlds[4][32], h1lds[4][32], h2lds[4][32];

    int tid = threadIdx.x;
    for (int i = tid; i < 1024; i += 256) {
        int j = i & 31, k = i >> 5;
        w1T[k][j] = qw128(w1[j * 32 + k]);
        w2T[k][j] = qw128(w2[j * 32 + k]);
    }
    if (tid < 96) { int k = tid & 31, j = tid >> 5; w3T[k][j] = qw128(w3[j * 32 + k]); }
    if (tid < 32) { b1q[tid] = qb16384(b1[tid]); b2q[tid] = qb16384(b2[tid]); }
    if (tid < 3)  b3q[tid] = qb16384(b3[tid]);
    __syncthreads();                                     // ONLY block-wide barrier

    int wv = tid >> 6, lane = tid & 63;
    int b = blockIdx.x * 4 + wv;                         // 2048 blocks * 4 waves = 8192 boards
    const int* bp = board + b * 450;

    // phase 1: pack 450 cells into 8x u64 via ballot (coalesced dword loads)
#pragma unroll
    for (int t = 0; t < 8; ++t) {
        int n = t * 64 + lane;
        int cell = (n < 450) ? bp[n] : 0;
        unsigned long long m = __ballot(cell != 0);
        if (lane == 0) ballots[wv][t] = m;
    }

    // phase 2: 169 window hashes; bit f=9c+3i+j of idx = cell(c, wi+i, wj+j)
#pragma unroll
    for (int t = 0; t < 3; ++t) {
        int w = t * 64 + lane;                           // covers [0,192)
        int wi = w / 13;
        int wj = w - wi * 13;
        int idx = 0;
#pragma unroll
        for (int c = 0; c < 2; ++c) {
#pragma unroll
            for (int i = 0; i < 3; ++i) {
                int s = c * 225 + (min(wi, 12) + i) * 15;  // clamp row for pad lanes
                int word = s >> 6, off = s & 63;
                unsigned long long lo = ballots[wv][word];
                unsigned long long hi = ballots[wv][word + 1];
                // (lo>>off)|(hi<<(64-off)); double-shift avoids UB, 0 at off==0
                unsigned long long bits = (lo >> off) | ((hi << 1) << (63 - off));
                idx |= (int)((bits >> wj) & 7ull) << (9 * c + 3 * i);
            }
        }
        hashoff[wv][w] = (w < NW) ? (idx << 5) : 0;      // pad -> row 0 (masked later)
    }

    // phase 3: gather-accumulate, branchless + fully unrolled for max loads in flight.
    // 2 lanes per row: lane bit0 picks 16B half; 32 groups; 6 iterations cover 192 slots.
    int d1 = lane & 1;
    int g = lane >> 1;
    const uint8_t* base = embq + d1 * 16;
    uint4 dv[6];
#pragma unroll
    for (int it = 0; it < 6; ++it) {                     // issue ALL loads first
        int w = it * 32 + g;
        dv[it] = *(const uint4*)(base + hashoff[wv][w]);
    }
    const uint32_t M = 0x00FF00FFu;
    uint32_t a0lo = 0, a0hi = 0, a1lo = 0, a1hi = 0;     // packed u16 pairs, +128/window bias
    uint32_t a2lo = 0, a2hi = 0, a3lo = 0, a3hi = 0;     // max 169*255 = 43095 < 2^16
#pragma unroll
    for (int it = 0; it < 6; ++it) {
        uint32_t x0 = dv[it].x, x1 = dv[it].y, x2 = dv[it].z, x3 = dv[it].w;
        if (it == 5) {                                   // only slots [160,169) valid here
            uint32_t keep = (160 + g < NW) ? 0xFFFFFFFFu : 0u;
            x0 &= keep; x1 &= keep; x2 &= keep; x3 &= keep;
        }
        a0lo += x0 & M; a0hi += (x0 >> 8) & M;
        a1lo += x1 & M; a1hi += (x1 >> 8) & M;
        a2lo += x2 & M; a2hi += (x2 >> 8) & M;
        a3lo += x3 & M; a3hi += (x3 >> 8) & M;
    }
    // reduce across 32 groups (lanes sharing d1)
#pragma unroll
    for (int off = 2; off <= 32; off <<= 1) {
        a0lo += __shfl_xor(a0lo, off); a0hi += __shfl_xor(a0hi, off);
        a1lo += __shfl_xor(a1lo, off); a1hi += __shfl_xor(a1hi, off);
        a2lo += __shfl_xor(a2lo, off); a2hi += __shfl_xor(a2hi, off);
        a3lo += __shfl_xor(a3lo, off); a3hi += __shfl_xor(a3hi, off);
    }
    if (lane < 2) {                                      // lane == d1: channels [16*d1, 16*d1+16)
        uint32_t lo[4] = {a0lo, a1lo, a2lo, a3lo};
        uint32_t hi[4] = {a0hi, a1hi, a2hi, a3hi};
#pragma unroll
        for (int j = 0; j < 4; ++j) {
            int c[4];
            c[0] = (int)(lo[j] & 0xFFFFu) - 21632;       // 128*169 bias
            c[1] = (int)(hi[j] & 0xFFFFu) - 21632;
            c[2] = (int)(lo[j] >> 16)     - 21632;
            c[3] = (int)(hi[j] >> 16)     - 21632;
#pragma unroll
            for (int u = 0; u < 4; ++u) {
                int cc = min(max(c[u], -128), 127);      // clip(v,-1,127/128) exactly
                vlds[wv][d1 * 16 + j * 4 + u] = (float)cc * 0.0078125f;
            }
        }
    }

    // MLP: lane jj in [0,32) computes output jj; halves split k, combine via shfl_xor(32)
    int jj = lane & 31, hf = lane >> 5;
    float s1 = 0.f;
#pragma unroll
    for (int k2 = 0; k2 < 16; ++k2) {
        int k = hf * 16 + k2;
        s1 = fmaf(vlds[wv][k], w1T[k][jj], s1);
    }
    s1 += __shfl_xor(s1, 32);
    s1 += b1q[jj];
    s1 = fminf(fmaxf(s1, 0.f), 0.9921875f);
    if (lane < 32) h1lds[wv][jj] = s1;

    float s2 = 0.f;
#pragma unroll
    for (int k2 = 0; k2 < 16; ++k2) {
        int k = hf * 16 + k2;
        s2 = fmaf(h1lds[wv][k], w2T[k][jj], s2);
    }
    s2 += __shfl_xor(s2, 32);
    s2 += b2q[jj];
    s2 = fminf(fmaxf(s2, 0.f), 0.9921875f);
    if (lane < 32) h2lds[wv][jj] = s2;

    float s3 = 0.f;
    if (jj < 3) {
#pragma unroll
        for (int k2 = 0; k2 < 16; ++k2) {
            int k = hf * 16 + k2;
            s3 = fmaf(h2lds[wv][k], w3T[k][jj], s3);
        }
    }
    s3 += __shfl_xor(s3, 32);
    if (lane < 3) vout[b * 3 + lane] = s3 + b3q[lane];
}

extern "C" void kernel_launch(void* const* d_in, const int* in_sizes, int n_in,
                              void* d_out, int out_size, void* d_ws, size_t ws_size,
                              hipStream_t stream) {
    const int*   board = (const int*)d_in[0];
    const float* emb   = (const float*)d_in[1];
    const float* w1    = (const float*)d_in[2];
    const float* b1    = (const float*)d_in[3];
    const float* w2    = (const float*)d_in[4];
    const float* b2    = (const float*)d_in[5];
    const float* w3    = (const float*)d_in[6];
    const float* b3    = (const float*)d_in[7];
    float* out = (float*)d_out;
    uint8_t* embq = (uint8_t*)d_ws;                      // 2^18 * 32 = 8.4 MB

    // v = out[0 : 8192*3], policy = out[24576 : 24576+1843200]
    prep_kernel<<<3848, 256, 0, stream>>>(emb, embq, (f32x4*)(out + 24576));
    nnue_kernel<<<2048, 256, 0, stream>>>(board, embq, w1, b1, w2, b2, w3, b3, out);
}